// Round 7
// baseline (184.915 us; speedup 1.0000x reference)
//
#include <hip/hip_runtime.h>
#include <hip/hip_bf16.h>
#include <math.h>

#define BB 4
#define CC 64
#define HH 160
#define WW 160
#define HWs (HH*WW)        // 25600
#define NPIX (BB*HWs)      // 102400

using bf16 = __hip_bfloat16;
typedef __attribute__((ext_vector_type(8)))  short short8v;    // 8 x bf16 bits
typedef __attribute__((ext_vector_type(16))) float float16v;   // 32x32 MFMA acc

__device__ __forceinline__ unsigned short f2bfu(float f){
    union { bf16 h; unsigned short u; } cv; cv.h = __float2bfloat16(f); return cv.u;
}
__device__ __forceinline__ float bfu2f(unsigned short u){
    union { float f; unsigned int i; } cv; cv.i = ((unsigned int)u)<<16; return cv.f;
}
__device__ __forceinline__ float16v fzero16(){
    float16v z;
    #pragma unroll
    for(int i=0;i<16;i++) z[i]=0.f;
    return z;
}

// ---- workspace layout (float offsets) ----
// All MFMA A-frags are for 32x32x16: A[m=lane&31][k=(lane>>5)*8+j]
constexpr int B1X1 = 0;        // 64   : summed dyn1d biases (fp32)
constexpr int SFBo = 64;       // 64   : BN-folded sf bias (fp32)
constexpr int SFWf = 128;      // 18432 fl = 36864 bf16 : sf A-frags [og][tap*4+kc][lane][j]
constexpr int BAWf = 18560;    // 9216 fl = 18432 bf16  : ba_w1 A-frags [tap*4+kc][lane][j]
constexpr int FUWf = 27776;    // 2048 fl = 4096 bf16   : dyn1d A-frags [og][kc][lane][j]
constexpr int FCWf = 29824;    // 2048 fl = 4096 bf16   : fc A-frags [og][kc][lane][j]
constexpr int WS_FLOATS = 31872;   // 127,488 B
// bf16 NHWC region after: XB [p][c] then FUS [p][c], each NPIX*64 elems (13.1 MB)

// ================= K0: weight prep (folds + 32x32 MFMA packs) =================
__global__ void k_prep(const float* __restrict__ rk5w, const float* __restrict__ rk5b,
                       const float* __restrict__ rk7w, const float* __restrict__ rk7b,
                       const float* __restrict__ lk5w, const float* __restrict__ lk5b,
                       const float* __restrict__ lk7w, const float* __restrict__ lk7b,
                       const float* __restrict__ sfw,  const float* __restrict__ sfb,
                       const float* __restrict__ bng,  const float* __restrict__ bnb,
                       const float* __restrict__ bnm,  const float* __restrict__ bnv,
                       const float* __restrict__ baw1, const float* __restrict__ fcw,
                       float* __restrict__ ws)
{
    int tid = blockIdx.x*blockDim.x + threadIdx.x;
    int nt  = gridDim.x*blockDim.x;
    // summed dyn1d biases
    for(int o=tid;o<64;o+=nt){
        int grp=o>>4, oo=o&15; int K=(grp&1)?7:5;
        const float* bp = (grp==0)?rk5b:(grp==1)?rk7b:(grp==2)?lk5b:lk7b;
        float s=0.f; for(int k=0;k<K;k++) s += bp[oo*K+k];
        ws[B1X1+o]=s;
    }
    // BN-folded sf bias
    for(int oc=tid;oc<64;oc+=nt){
        float sc = bng[oc]*rsqrtf(bnv[oc]+1e-5f);
        ws[SFBo+oc] = sfb[oc]*sc + bnb[oc] - bnm[oc]*sc;
    }
    // sf A-frags: idx = og*18432 + (tap*4+kc)*512 + lane*8 + j
    unsigned short* sfwf = (unsigned short*)(ws + SFWf);
    for(int idx=tid; idx<36864; idx+=nt){
        int og = idx/18432;  int rem = idx - og*18432;
        int f  = rem>>9;     int r2 = rem & 511;
        int lane = r2>>3;    int j = r2&7;
        int tap = f>>2, kc = f&3;
        int oc = og*32 + (lane&31);
        int ic = kc*16 + (lane>>5)*8 + j;
        float sc = bng[oc]*rsqrtf(bnv[oc]+1e-5f);
        sfwf[idx] = f2bfu(sfw[(oc*64+ic)*9 + tap] * sc);
    }
    // ba_w1 A-frags: idx = (tap*4+kc)*512 + lane*8 + j  (M=32 = all attn oc)
    unsigned short* bawf = (unsigned short*)(ws + BAWf);
    for(int idx=tid; idx<18432; idx+=nt){
        int f  = idx>>9;     int r2 = idx & 511;
        int lane = r2>>3;    int j = r2&7;
        int tap = f>>2, kc = f&3;
        int oc = lane&31;
        int ic = kc*16 + (lane>>5)*8 + j;
        bawf[idx] = f2bfu(baw1[(oc*64+ic)*9 + tap]);
    }
    // dyn1d 1x1 (k-summed) A-frags: idx = og*2048 + kc*512 + lane*8 + j
    unsigned short* fuwf = (unsigned short*)(ws + FUWf);
    for(int idx=tid; idx<4096; idx+=nt){
        int og   = idx>>11;
        int kc   = (idx>>9)&3;
        int lane = (idx>>3)&63;
        int j    = idx&7;
        int oc = og*32 + (lane&31);
        int c  = kc*16 + (lane>>5)*8 + j;
        int grp = oc>>4, oo = oc&15; int K = (grp&1)?7:5;
        const float* w = (grp==0)?rk5w:(grp==1)?rk7w:(grp==2)?lk5w:lk7w;
        float s = 0.f;
        for(int k=0;k<K;k++) s += w[(oo*K+k)*64 + c];
        fuwf[idx] = f2bfu(s);
    }
    // fc A-frags (same indexing)
    unsigned short* fcwf = (unsigned short*)(ws + FCWf);
    for(int idx=tid; idx<4096; idx+=nt){
        int og   = idx>>11;
        int kc   = (idx>>9)&3;
        int lane = (idx>>3)&63;
        int j    = idx&7;
        int oc = og*32 + (lane&31);
        int c  = kc*16 + (lane>>5)*8 + j;
        fcwf[idx] = f2bfu(fcw[oc*64 + c]);
    }
}

// ============ K1: x (fp32 NCHW) -> XB (bf16 NHWC), swizzled LDS transpose ============
__global__ __launch_bounds__(256)
void k_x2nhwc(const float* __restrict__ x, unsigned short* __restrict__ xb)
{
    __shared__ unsigned short ls[128*72];
    const int t = threadIdx.x;
    const int p0 = blockIdx.x*128;
    const int b = p0 / HWs, pp0 = p0 % HWs;
    const float* xbase = x + (size_t)b*CC*HWs + pp0;
    #pragma unroll
    for(int iter=0; iter<32; iter++){
        int idx = iter*256 + t;
        int c = idx>>7, px = idx&127;
        int bs = (c>>3) ^ ((px>>3)&7);
        ls[px*72 + bs*8 + (c&7)] = f2bfu(xbase[(size_t)c*HWs + px]);
    }
    __syncthreads();
    #pragma unroll
    for(int iter=0; iter<4; iter++){
        int idx = iter*256 + t;
        int sub = idx&7, px = idx>>3;
        int bs = sub ^ ((px>>3)&7);
        short8v v = *(short8v*)(ls + px*72 + bs*8);
        *(short8v*)(xb + ((size_t)(p0+px))*64 + sub*8) = v;
    }
}

// ====== K2: fused attn-conv + sobel + sigmoid + channel-sum + dyn1d -> FUS ======
// 16x8 px tile, 256 thr, 4 waves; all matmuls are 32x32x16 MFMA (N=32 = row-pair).
__global__ __launch_bounds__(256)
void k_fuseA(const unsigned short* __restrict__ xb, const float* __restrict__ bab1,
             const float* __restrict__ baw2, const float* __restrict__ bab2,
             const float* __restrict__ ws, unsigned short* __restrict__ fus)
{
    __shared__ unsigned short tile[10*18*72];  // 25,920 B
    __shared__ float zbuf[8][16];
    __shared__ float ebuf[2][128];
    __shared__ float sxbuf[8][16];
    __shared__ float pbuf[128], qbuf[128];
    const int bw = blockIdx.x, bh = blockIdx.y, b = blockIdx.z;
    const int t = threadIdx.x;
    const int wave = t>>6, lane = t&63;
    const int half = lane>>5, n = lane&31;
    const int w0 = bw*16, h0 = bh*8;

    const unsigned short* fb = xb + (size_t)b*HWs*64;
    for(int idx=t; idx<1440; idx+=256){
        int sub = idx&7; int pix = idx>>3;
        int row = pix/18, col = pix%18;
        int gh = h0-1+row, gw = w0-1+col;
        short8v v = {0,0,0,0,0,0,0,0};
        if(gh>=0&&gh<HH&&gw>=0&&gw<WW)
            v = *(const short8v*)(fb + ((size_t)(gh*WW+gw))*64 + sub*8);
        *(short8v*)(tile + (row*18+col)*72 + sub*8) = v;
    }
    // per-lane epilogue constants (D row = (r&3)+8*(r>>2)+4*half)
    float b1v[16], w2v[16];
    #pragma unroll
    for(int r=0;r<16;r++){
        int oc = (r&3) + 8*(r>>2) + 4*half;
        b1v[r] = bab1[oc];
        w2v[r] = baw2[oc];
    }
    __syncthreads();

    const unsigned short* bawf = (const unsigned short*)(ws + BAWf);
    // --- attn conv: wave handles row-pair `wave` (rows 2w, 2w+1), M=32 oc ---
    {
        const int rbase = 2*wave + (n>>4);   // this lane's output row
        const int cbase = n&15;
        float16v acc = fzero16();
        #pragma unroll
        for(int kc=0; kc<4; kc++){
            short8v af[9];
            #pragma unroll
            for(int tap=0; tap<9; tap++)
                af[tap] = *(const short8v*)(bawf + (((size_t)(tap*4+kc))*64 + lane)*8);
            #pragma unroll
            for(int tap=0; tap<9; tap++){
                const int dh = tap/3, dw = tap%3;
                short8v bf = *(const short8v*)(tile + ((rbase+dh)*18 + cbase+dw)*72
                                               + kc*16 + half*8);
                acc = __builtin_amdgcn_mfma_f32_32x32x16_bf16(af[tap], bf, acc, 0,0,0);
            }
        }
        float cz = 0.f;
        #pragma unroll
        for(int r=0;r<16;r++) cz += fmaxf(acc[r]+b1v[r],0.f)*w2v[r];
        cz += __shfl_xor(cz, 32);
        if(lane < 32) zbuf[2*wave + (n>>4)][n&15] = cz;
    }
    // --- channel sum via ones-A MFMA (center pixels of the same row-pair) ---
    {
        short8v ones;
        #pragma unroll
        for(int j=0;j<8;j++) ones[j] = (short)0x3F80;
        float16v s = fzero16();
        const int rr = 2*wave + (n>>4) + 1, cc = (n&15) + 1;
        #pragma unroll
        for(int kc=0; kc<4; kc++){
            short8v bf = *(const short8v*)(tile + (rr*18 + cc)*72 + kc*16 + half*8);
            s = __builtin_amdgcn_mfma_f32_32x32x16_bf16(ones, bf, s, 0,0,0);
        }
        if(lane < 32) sxbuf[2*wave + (n>>4)][n&15] = s[0];  // D row 0 lives in half=0,reg0
    }
    // --- Sobel edge from the same LDS tile ---
    {
        const int hf = t>>7, px = t&127;
        const int r = px>>4, c = px&15;
        float e = 0.f;
        #pragma unroll
        for(int s=0; s<4; s++){
            const int sub = hf*4 + s;
            if(hf==0){
                short8v a0 = *(const short8v*)(tile + ((r  )*18 + c  )*72 + sub*8);
                short8v a2 = *(const short8v*)(tile + ((r  )*18 + c+2)*72 + sub*8);
                short8v a3 = *(const short8v*)(tile + ((r+1)*18 + c  )*72 + sub*8);
                short8v a5 = *(const short8v*)(tile + ((r+1)*18 + c+2)*72 + sub*8);
                short8v a6 = *(const short8v*)(tile + ((r+2)*18 + c  )*72 + sub*8);
                short8v a8 = *(const short8v*)(tile + ((r+2)*18 + c+2)*72 + sub*8);
                #pragma unroll
                for(int j=0;j<8;j++){
                    float gx = (bfu2f((unsigned short)a2[j]) - bfu2f((unsigned short)a0[j]))
                       + 2.f*(bfu2f((unsigned short)a5[j]) - bfu2f((unsigned short)a3[j]))
                       +      (bfu2f((unsigned short)a8[j]) - bfu2f((unsigned short)a6[j]));
                    e += fabsf(gx);
                }
            } else {
                short8v b0 = *(const short8v*)(tile + ((r  )*18 + c  )*72 + sub*8);
                short8v b1 = *(const short8v*)(tile + ((r  )*18 + c+1)*72 + sub*8);
                short8v b2 = *(const short8v*)(tile + ((r  )*18 + c+2)*72 + sub*8);
                short8v b6 = *(const short8v*)(tile + ((r+2)*18 + c  )*72 + sub*8);
                short8v b7 = *(const short8v*)(tile + ((r+2)*18 + c+1)*72 + sub*8);
                short8v b8 = *(const short8v*)(tile + ((r+2)*18 + c+2)*72 + sub*8);
                #pragma unroll
                for(int j=0;j<8;j++){
                    float gy = (bfu2f((unsigned short)b6[j]) - bfu2f((unsigned short)b0[j]))
                       + 2.f*(bfu2f((unsigned short)b7[j]) - bfu2f((unsigned short)b1[j]))
                       +      (bfu2f((unsigned short)b8[j]) - bfu2f((unsigned short)b2[j]));
                    e += fabsf(gy);
                }
            }
        }
        ebuf[hf][px] = e;
    }
    __syncthreads();

    // --- per-pixel scalars: A = 1+sigmoid(z), P = A^2*sx, Q = A*sx ---
    if(t < 128){
        const int row = t>>4, col = t&15;
        float z = zbuf[row][col] + bab2[0]
                + (ebuf[0][t] + ebuf[1][t]) * (1.f/32.f);
        float A = 1.f + 1.f/(1.f+__expf(-z));
        float S = A * sxbuf[row][col];
        pbuf[t] = A*S;
        qbuf[t] = S;
    }
    __syncthreads();

    // --- dyn1d 1x1 via MFMA: fus_oc = P*dot + Q*b; wave: og=w&1, rps {w>>1, w>>1+2} ---
    {
        const int og = wave&1;
        const unsigned short* fuwf = (const unsigned short*)(ws + FUWf);
        short8v wf[4];
        #pragma unroll
        for(int kc=0; kc<4; kc++)
            wf[kc] = *(const short8v*)(fuwf + (((size_t)og*4 + kc)*64 + lane)*8);
        float bqv[16];
        #pragma unroll
        for(int r=0;r<16;r++) bqv[r] = ws[B1X1 + og*32 + (r&3)+8*(r>>2)+4*half];
        #pragma unroll
        for(int t2=0; t2<2; t2++){
            const int rp = (wave>>1) + 2*t2;
            const int row = 2*rp + (n>>4), col = n&15;
            float16v a = fzero16();
            #pragma unroll
            for(int kc=0; kc<4; kc++){
                short8v bf = *(const short8v*)(tile + ((row+1)*18 + col+1)*72
                                               + kc*16 + half*8);
                a = __builtin_amdgcn_mfma_f32_32x32x16_bf16(wf[kc], bf, a, 0,0,0);
            }
            const float P = pbuf[row*16+col], Q = qbuf[row*16+col];
            unsigned short* base = fus + ((size_t)b*HWs + (h0+row)*WW + w0+col)*64
                                   + og*32 + 4*half;
            #pragma unroll
            for(int g=0; g<4; g++){
                union { unsigned long long u; unsigned short s[4]; } pk;
                #pragma unroll
                for(int rr=0; rr<4; rr++)
                    pk.s[rr] = f2bfu(P*a[4*g+rr] + Q*bqv[4*g+rr]);
                *(unsigned long long*)(base + 8*g) = pk.u;
            }
        }
    }
}

// ====== K3: fused sf 3x3 conv (MFMA) + ReLU + fc 1x1 (MFMA) + residual -> out ======
__global__ __launch_bounds__(256)
void k_fuseB(const unsigned short* __restrict__ fus, const float* __restrict__ ws,
             const float* __restrict__ fcb, const float* __restrict__ x,
             float* __restrict__ out)
{
    __shared__ unsigned short ftile[10*18*72];  // 25,920 B
    __shared__ unsigned short ytile[128*72];    // 18,432 B
    const int bw = blockIdx.x, bh = blockIdx.y, b = blockIdx.z;
    const int t  = threadIdx.x;
    const int wave = t>>6, lane = t&63;
    const int half = lane>>5, n = lane&31;
    const int og = wave&1;
    const int w0 = bw*16, h0 = bh*8;

    const unsigned short* fb = fus + (size_t)b*HWs*64;
    for(int idx=t; idx<1440; idx+=256){
        int sub = idx&7; int pix = idx>>3;
        int row = pix/18, col = pix%18;
        int gh = h0-1+row, gw = w0-1+col;
        short8v v = {0,0,0,0,0,0,0,0};
        if(gh>=0&&gh<HH&&gw>=0&&gw<WW)
            v = *(const short8v*)(fb + ((size_t)(gh*WW+gw))*64 + sub*8);
        *(short8v*)(ftile + (row*18+col)*72 + sub*8) = v;
    }
    float biasv[16];
    #pragma unroll
    for(int r=0;r<16;r++) biasv[r] = ws[SFBo + og*32 + (r&3)+8*(r>>2)+4*half];
    __syncthreads();

    // --- sf conv: wave handles og and row-pairs {w>>1, w>>1+2} simultaneously ---
    const unsigned short* sfwf = (const unsigned short*)(ws + SFWf);
    const int rp0 = wave>>1, rp1 = rp0+2;
    const int row0 = 2*rp0 + (n>>4), row1 = 2*rp1 + (n>>4), col = n&15;
    {
        float16v A0 = fzero16(), A1 = fzero16();
        #pragma unroll
        for(int kc=0; kc<4; kc++){
            short8v af[9];
            #pragma unroll
            for(int tap=0; tap<9; tap++)
                af[tap] = *(const short8v*)(sfwf + (((size_t)og*36 + tap*4+kc)*64 + lane)*8);
            #pragma unroll
            for(int tap=0; tap<9; tap++){
                const int dh = tap/3, dw = tap%3;
                short8v b0 = *(const short8v*)(ftile + ((row0+dh)*18 + col+dw)*72
                                               + kc*16 + half*8);
                short8v b1 = *(const short8v*)(ftile + ((row1+dh)*18 + col+dw)*72
                                               + kc*16 + half*8);
                A0 = __builtin_amdgcn_mfma_f32_32x32x16_bf16(af[tap], b0, A0, 0,0,0);
                A1 = __builtin_amdgcn_mfma_f32_32x32x16_bf16(af[tap], b1, A1, 0,0,0);
            }
        }
        // relu -> bf16 -> ytile (NHWC, 72-stride)
        unsigned short* y0 = ytile + (row0*16+col)*72 + og*32 + 4*half;
        unsigned short* y1p = ytile + (row1*16+col)*72 + og*32 + 4*half;
        #pragma unroll
        for(int g=0; g<4; g++){
            union { unsigned long long u; unsigned short s[4]; } pk0, pk1;
            #pragma unroll
            for(int rr=0; rr<4; rr++){
                pk0.s[rr] = f2bfu(fmaxf(A0[4*g+rr] + biasv[4*g+rr], 0.f));
                pk1.s[rr] = f2bfu(fmaxf(A1[4*g+rr] + biasv[4*g+rr], 0.f));
            }
            *(unsigned long long*)(y0  + 8*g) = pk0.u;
            *(unsigned long long*)(y1p + 8*g) = pk1.u;
        }
    }
    __syncthreads();

    // --- fc 1x1 MFMA + bias + residual -> fp32 NCHW out ---
    {
        const unsigned short* fcwf = (const unsigned short*)(ws + FCWf);
        short8v ff[4];
        #pragma unroll
        for(int kc=0; kc<4; kc++)
            ff[kc] = *(const short8v*)(fcwf + (((size_t)og*4 + kc)*64 + lane)*8);
        float fcbv[16];
        #pragma unroll
        for(int r=0;r<16;r++) fcbv[r] = fcb[og*32 + (r&3)+8*(r>>2)+4*half];
        #pragma unroll
        for(int t2=0; t2<2; t2++){
            const int rp = (wave>>1) + 2*t2;
            const int row = 2*rp + (n>>4);
            const int px = row*16 + col;
            float16v F = fzero16();
            #pragma unroll
            for(int kc=0; kc<4; kc++){
                short8v bf = *(const short8v*)(ytile + px*72 + kc*16 + half*8);
                F = __builtin_amdgcn_mfma_f32_32x32x16_bf16(ff[kc], bf, F, 0,0,0);
            }
            #pragma unroll
            for(int r=0;r<16;r++){
                int oc = og*32 + (r&3)+8*(r>>2)+4*half;
                size_t g = ((size_t)(b*CC + oc))*HWs + (h0+row)*WW + w0 + col;
                out[g] = F[r] + fcbv[r] + x[g];
            }
        }
    }
}

extern "C" void kernel_launch(void* const* d_in, const int* in_sizes, int n_in,
                              void* d_out, int out_size, void* d_ws, size_t ws_size,
                              hipStream_t stream)
{
    const float* x     = (const float*)d_in[0];
    const float* ba_w1 = (const float*)d_in[1];
    const float* ba_b1 = (const float*)d_in[2];
    const float* ba_w2 = (const float*)d_in[3];
    const float* ba_b2 = (const float*)d_in[4];
    // d_in[5..12] = offset branch: dead code in the reference (never reaches the output)
    const float* rk5_w = (const float*)d_in[13];
    const float* rk5_b = (const float*)d_in[14];
    const float* rk7_w = (const float*)d_in[15];
    const float* rk7_b = (const float*)d_in[16];
    const float* lk5_w = (const float*)d_in[17];
    const float* lk5_b = (const float*)d_in[18];
    const float* lk7_w = (const float*)d_in[19];
    const float* lk7_b = (const float*)d_in[20];
    const float* sf_w  = (const float*)d_in[21];
    const float* sf_b  = (const float*)d_in[22];
    const float* bng   = (const float*)d_in[23];
    const float* bnb   = (const float*)d_in[24];
    const float* bnm   = (const float*)d_in[25];
    const float* bnv   = (const float*)d_in[26];
    const float* fc_w  = (const float*)d_in[27];
    const float* fc_b  = (const float*)d_in[28];

    float* wsf = (float*)d_ws;
    unsigned short* XB  = (unsigned short*)((char*)d_ws + (size_t)WS_FLOATS*4);
    unsigned short* FUS = XB + (size_t)NPIX*64;
    float* out = (float*)d_out;

    k_prep<<<64, 256, 0, stream>>>(rk5_w,rk5_b,rk7_w,rk7_b,lk5_w,lk5_b,lk7_w,lk7_b,
                                   sf_w,sf_b,bng,bnb,bnm,bnv, ba_w1, fc_w, wsf);
    k_x2nhwc<<<NPIX/128, 256, 0, stream>>>(x, XB);
    k_fuseA<<<dim3(10,20,4), 256, 0, stream>>>(XB, ba_b1, ba_w2, ba_b2, wsf, FUS);
    k_fuseB<<<dim3(10,20,4), 256, 0, stream>>>(FUS, wsf, fc_b, x, out);
}

// Round 8
// 176.810 us; speedup vs baseline: 1.0458x; 1.0458x over previous
//
#include <hip/hip_runtime.h>
#include <hip/hip_bf16.h>
#include <math.h>

#define BB 4
#define CC 64
#define HH 160
#define WW 160
#define HWs (HH*WW)        // 25600
#define NPIX (BB*HWs)      // 102400

using bf16 = __hip_bfloat16;
typedef __attribute__((ext_vector_type(8)))  short short8v;    // 8 x bf16 bits
typedef __attribute__((ext_vector_type(16))) float float16v;   // 32x32 MFMA acc

__device__ __forceinline__ unsigned short f2bfu(float f){
    union { bf16 h; unsigned short u; } cv; cv.h = __float2bfloat16(f); return cv.u;
}
__device__ __forceinline__ float bfu2f(unsigned short u){
    union { float f; unsigned int i; } cv; cv.i = ((unsigned int)u)<<16; return cv.f;
}
__device__ __forceinline__ float16v fzero16(){
    float16v z;
    #pragma unroll
    for(int i=0;i<16;i++) z[i]=0.f;
    return z;
}

// ---- workspace layout (float offsets) ----
// All MFMA frags are 32x32x16: A[m=lane&31][k=(lane>>5)*8+j]; D col=lane&31,
// row=(r&3)+8*(r>>2)+4*(lane>>5)  [verified in-pipeline R7]
constexpr int B1X1 = 0;        // 64   : summed dyn1d biases (fp32)
constexpr int SFBo = 64;       // 64   : BN-folded sf bias (fp32)
constexpr int SFWf = 128;      // 18432 fl = 36864 bf16 : sf A-frags [og][tap*4+kc][lane][j]
constexpr int BAWf = 18560;    // 9216 fl = 18432 bf16  : ba_w1 A-frags [tap*4+kc][lane][j]
constexpr int FUWf = 27776;    // 2048 fl = 4096 bf16   : dyn1d A-frags [og][kc][lane][j]
constexpr int FCWf = 29824;    // 2048 fl = 4096 bf16   : fc A-frags [og][kc][lane][j]
constexpr int WS_FLOATS = 31872;   // 127,488 B
// bf16 NHWC region after: XB [p][c] then FUS [p][c], each NPIX*64 elems (13.1 MB)

// ================= K0: weight prep (folds + 32x32 MFMA packs) =================
__global__ void k_prep(const float* __restrict__ rk5w, const float* __restrict__ rk5b,
                       const float* __restrict__ rk7w, const float* __restrict__ rk7b,
                       const float* __restrict__ lk5w, const float* __restrict__ lk5b,
                       const float* __restrict__ lk7w, const float* __restrict__ lk7b,
                       const float* __restrict__ sfw,  const float* __restrict__ sfb,
                       const float* __restrict__ bng,  const float* __restrict__ bnb,
                       const float* __restrict__ bnm,  const float* __restrict__ bnv,
                       const float* __restrict__ baw1, const float* __restrict__ fcw,
                       float* __restrict__ ws)
{
    int tid = blockIdx.x*blockDim.x + threadIdx.x;
    int nt  = gridDim.x*blockDim.x;
    for(int o=tid;o<64;o+=nt){
        int grp=o>>4, oo=o&15; int K=(grp&1)?7:5;
        const float* bp = (grp==0)?rk5b:(grp==1)?rk7b:(grp==2)?lk5b:lk7b;
        float s=0.f; for(int k=0;k<K;k++) s += bp[oo*K+k];
        ws[B1X1+o]=s;
    }
    for(int oc=tid;oc<64;oc+=nt){
        float sc = bng[oc]*rsqrtf(bnv[oc]+1e-5f);
        ws[SFBo+oc] = sfb[oc]*sc + bnb[oc] - bnm[oc]*sc;
    }
    unsigned short* sfwf = (unsigned short*)(ws + SFWf);
    for(int idx=tid; idx<36864; idx+=nt){
        int og = idx/18432;  int rem = idx - og*18432;
        int f  = rem>>9;     int r2 = rem & 511;
        int lane = r2>>3;    int j = r2&7;
        int tap = f>>2, kc = f&3;
        int oc = og*32 + (lane&31);
        int ic = kc*16 + (lane>>5)*8 + j;
        float sc = bng[oc]*rsqrtf(bnv[oc]+1e-5f);
        sfwf[idx] = f2bfu(sfw[(oc*64+ic)*9 + tap] * sc);
    }
    unsigned short* bawf = (unsigned short*)(ws + BAWf);
    for(int idx=tid; idx<18432; idx+=nt){
        int f  = idx>>9;     int r2 = idx & 511;
        int lane = r2>>3;    int j = r2&7;
        int tap = f>>2, kc = f&3;
        int oc = lane&31;
        int ic = kc*16 + (lane>>5)*8 + j;
        bawf[idx] = f2bfu(baw1[(oc*64+ic)*9 + tap]);
    }
    unsigned short* fuwf = (unsigned short*)(ws + FUWf);
    for(int idx=tid; idx<4096; idx+=nt){
        int og   = idx>>11;
        int kc   = (idx>>9)&3;
        int lane = (idx>>3)&63;
        int j    = idx&7;
        int oc = og*32 + (lane&31);
        int c  = kc*16 + (lane>>5)*8 + j;
        int grp = oc>>4, oo = oc&15; int K = (grp&1)?7:5;
        const float* w = (grp==0)?rk5w:(grp==1)?rk7w:(grp==2)?lk5w:lk7w;
        float s = 0.f;
        for(int k=0;k<K;k++) s += w[(oo*K+k)*64 + c];
        fuwf[idx] = f2bfu(s);
    }
    unsigned short* fcwf = (unsigned short*)(ws + FCWf);
    for(int idx=tid; idx<4096; idx+=nt){
        int og   = idx>>11;
        int kc   = (idx>>9)&3;
        int lane = (idx>>3)&63;
        int j    = idx&7;
        int oc = og*32 + (lane&31);
        int c  = kc*16 + (lane>>5)*8 + j;
        fcwf[idx] = f2bfu(fcw[oc*64 + c]);
    }
}

// ============ K1: x (fp32 NCHW) -> XB (bf16 NHWC), float4 loads + LDS transpose ============
__global__ __launch_bounds__(256)
void k_x2nhwc(const float* __restrict__ x, unsigned short* __restrict__ xb)
{
    __shared__ unsigned short ls[128*72];
    const int t = threadIdx.x;
    const int p0 = blockIdx.x*128;
    const int b = p0 / HWs, pp0 = p0 % HWs;
    const float4* xb4 = (const float4*)(x + (size_t)b*CC*HWs + pp0);
    #pragma unroll
    for(int iter=0; iter<8; iter++){
        int idx = iter*256 + t;
        int c = idx>>5, g = idx&31;          // 64 ch x 32 float4-groups
        float4 v = xb4[(size_t)c*(HWs/4) + g];
        int px = g*4;
        int bs = (c>>3) ^ ((g>>1)&7);        // same swizzle for px..px+3
        unsigned short* base = ls + bs*8 + (c&7);
        base[(px+0)*72] = f2bfu(v.x);
        base[(px+1)*72] = f2bfu(v.y);
        base[(px+2)*72] = f2bfu(v.z);
        base[(px+3)*72] = f2bfu(v.w);
    }
    __syncthreads();
    #pragma unroll
    for(int iter=0; iter<4; iter++){
        int idx = iter*256 + t;
        int sub = idx&7, px = idx>>3;
        int bs = sub ^ ((px>>3)&7);
        short8v v = *(short8v*)(ls + px*72 + bs*8);
        *(short8v*)(xb + ((size_t)(p0+px))*64 + sub*8) = v;
    }
}

// ====== K2: fused attn-conv + sobel + sigmoid + channel-sum + dyn1d -> FUS ======
// 16x8 px tile, 4 waves, wave w owns row-pair w (both og). 2 barriers, z/sx in regs.
__global__ __launch_bounds__(256)
void k_fuseA(const unsigned short* __restrict__ xb, const float* __restrict__ bab1,
             const float* __restrict__ baw2, const float* __restrict__ bab2,
             const float* __restrict__ ws, unsigned short* __restrict__ fus)
{
    __shared__ unsigned short tile[10*18*72];  // 25,920 B
    __shared__ float ebuf[2][128];
    const int bw = blockIdx.x, bh = blockIdx.y, b = blockIdx.z;
    const int t = threadIdx.x;
    const int wave = t>>6, lane = t&63;
    const int half = lane>>5, n = lane&31;
    const int w0 = bw*16, h0 = bh*8;

    const unsigned short* fb = xb + (size_t)b*HWs*64;
    for(int idx=t; idx<1440; idx+=256){
        int sub = idx&7; int pix = idx>>3;
        int row = pix/18, col = pix%18;
        int gh = h0-1+row, gw = w0-1+col;
        short8v v = {0,0,0,0,0,0,0,0};
        if(gh>=0&&gh<HH&&gw>=0&&gw<WW)
            v = *(const short8v*)(fb + ((size_t)(gh*WW+gw))*64 + sub*8);
        *(short8v*)(tile + (row*18+col)*72 + sub*8) = v;
    }
    float b1v[16], w2v[16];
    #pragma unroll
    for(int r=0;r<16;r++){
        int oc = (r&3) + 8*(r>>2) + 4*half;
        b1v[r] = bab1[oc];
        w2v[r] = baw2[oc];
    }
    __syncthreads();

    const int row = 2*wave + (n>>4), col = n&15;   // this lane's pixel (all phases)

    // --- attn conv (M=32 oc), z stays in regs ---
    float cz;
    {
        const unsigned short* bawf = (const unsigned short*)(ws + BAWf);
        float16v acc = fzero16();
        #pragma unroll
        for(int kc=0; kc<4; kc++){
            short8v af[9];
            #pragma unroll
            for(int tap=0; tap<9; tap++)
                af[tap] = *(const short8v*)(bawf + (((size_t)(tap*4+kc))*64 + lane)*8);
            #pragma unroll
            for(int tap=0; tap<9; tap++){
                const int dh = tap/3, dw = tap%3;
                short8v bf = *(const short8v*)(tile + ((row+dh)*18 + col+dw)*72
                                               + kc*16 + half*8);
                acc = __builtin_amdgcn_mfma_f32_32x32x16_bf16(af[tap], bf, acc, 0,0,0);
            }
        }
        cz = 0.f;
        #pragma unroll
        for(int r=0;r<16;r++) cz += fmaxf(acc[r]+b1v[r],0.f)*w2v[r];
        cz += __shfl_xor(cz, 32);
    }
    // --- channel sum via ones-A MFMA (every D row = colsum) ---
    float sx;
    {
        short8v ones;
        #pragma unroll
        for(int j=0;j<8;j++) ones[j] = (short)0x3F80;
        float16v s = fzero16();
        #pragma unroll
        for(int kc=0; kc<4; kc++){
            short8v bf = *(const short8v*)(tile + ((row+1)*18 + col+1)*72 + kc*16 + half*8);
            s = __builtin_amdgcn_mfma_f32_32x32x16_bf16(ones, bf, s, 0,0,0);
        }
        sx = s[0];
    }
    // --- Sobel edge (2 threads/px over channel halves) ---
    {
        const int hf = t>>7, px = t&127;
        const int r = px>>4, c = px&15;
        float e = 0.f;
        #pragma unroll
        for(int s=0; s<4; s++){
            const int sub = hf*4 + s;
            if(hf==0){
                short8v a0 = *(const short8v*)(tile + ((r  )*18 + c  )*72 + sub*8);
                short8v a2 = *(const short8v*)(tile + ((r  )*18 + c+2)*72 + sub*8);
                short8v a3 = *(const short8v*)(tile + ((r+1)*18 + c  )*72 + sub*8);
                short8v a5 = *(const short8v*)(tile + ((r+1)*18 + c+2)*72 + sub*8);
                short8v a6 = *(const short8v*)(tile + ((r+2)*18 + c  )*72 + sub*8);
                short8v a8 = *(const short8v*)(tile + ((r+2)*18 + c+2)*72 + sub*8);
                #pragma unroll
                for(int j=0;j<8;j++){
                    float gx = (bfu2f((unsigned short)a2[j]) - bfu2f((unsigned short)a0[j]))
                       + 2.f*(bfu2f((unsigned short)a5[j]) - bfu2f((unsigned short)a3[j]))
                       +      (bfu2f((unsigned short)a8[j]) - bfu2f((unsigned short)a6[j]));
                    e += fabsf(gx);
                }
            } else {
                short8v b0 = *(const short8v*)(tile + ((r  )*18 + c  )*72 + sub*8);
                short8v b1 = *(const short8v*)(tile + ((r  )*18 + c+1)*72 + sub*8);
                short8v b2 = *(const short8v*)(tile + ((r  )*18 + c+2)*72 + sub*8);
                short8v b6 = *(const short8v*)(tile + ((r+2)*18 + c  )*72 + sub*8);
                short8v b7 = *(const short8v*)(tile + ((r+2)*18 + c+1)*72 + sub*8);
                short8v b8 = *(const short8v*)(tile + ((r+2)*18 + c+2)*72 + sub*8);
                #pragma unroll
                for(int j=0;j<8;j++){
                    float gy = (bfu2f((unsigned short)b6[j]) - bfu2f((unsigned short)b0[j]))
                       + 2.f*(bfu2f((unsigned short)b7[j]) - bfu2f((unsigned short)b1[j]))
                       +      (bfu2f((unsigned short)b8[j]) - bfu2f((unsigned short)b2[j]));
                    e += fabsf(gy);
                }
            }
        }
        ebuf[hf][px] = e;
    }
    __syncthreads();

    // --- per-lane scalars: A = 1+sigmoid(z), P = A^2*sx, Q = A*sx ---
    const int pxl = row*16 + col;
    float z = cz + bab2[0] + (ebuf[0][pxl] + ebuf[1][pxl]) * (1.f/32.f);
    float A = 1.f + 1.f/(1.f+__expf(-z));
    float Q = A * sx;
    float P = A * Q;

    // --- dyn1d 1x1 via MFMA, both og per wave ---
    const unsigned short* fuwf = (const unsigned short*)(ws + FUWf);
    #pragma unroll
    for(int og=0; og<2; og++){
        float16v a = fzero16();
        #pragma unroll
        for(int kc=0; kc<4; kc++){
            short8v wf = *(const short8v*)(fuwf + (((size_t)og*4 + kc)*64 + lane)*8);
            short8v bf = *(const short8v*)(tile + ((row+1)*18 + col+1)*72 + kc*16 + half*8);
            a = __builtin_amdgcn_mfma_f32_32x32x16_bf16(wf, bf, a, 0,0,0);
        }
        float bq[16];
        #pragma unroll
        for(int r=0;r<16;r++) bq[r] = ws[B1X1 + og*32 + (r&3)+8*(r>>2)+4*half];
        unsigned short* base = fus + ((size_t)b*HWs + (h0+row)*WW + w0+col)*64
                               + og*32 + 4*half;
        #pragma unroll
        for(int g=0; g<4; g++){
            union { unsigned long long u; unsigned short s[4]; } pk;
            #pragma unroll
            for(int rr=0; rr<4; rr++)
                pk.s[rr] = f2bfu(P*a[4*g+rr] + Q*bq[4*g+rr]);
            *(unsigned long long*)(base + 8*g) = pk.u;
        }
    }
}

// ====== K3: fused sf 3x3 conv + ReLU + fc 1x1 + residual -> out, NO ytile ======
// Y moves D-layout -> fc B-layout in-register: j<4 from half0 lane, j>=4 from half1
// lane (same px), reg = (j&3)+8*(kc&1)+4*H  -> one shfl_xor(32) pair per kc.
__global__ __launch_bounds__(256)
void k_fuseB(const unsigned short* __restrict__ fus, const float* __restrict__ ws,
             const float* __restrict__ fcb, const float* __restrict__ x,
             float* __restrict__ out)
{
    __shared__ unsigned short ftile[10*18*72];  // 25,920 B (only LDS)
    const int bw = blockIdx.x, bh = blockIdx.y, b = blockIdx.z;
    const int t  = threadIdx.x;
    const int wave = t>>6, lane = t&63;
    const int half = lane>>5, n = lane&31;
    const int w0 = bw*16, h0 = bh*8;

    const unsigned short* fb = fus + (size_t)b*HWs*64;
    for(int idx=t; idx<1440; idx+=256){
        int sub = idx&7; int pix = idx>>3;
        int row = pix/18, col = pix%18;
        int gh = h0-1+row, gw = w0-1+col;
        short8v v = {0,0,0,0,0,0,0,0};
        if(gh>=0&&gh<HH&&gw>=0&&gw<WW)
            v = *(const short8v*)(fb + ((size_t)(gh*WW+gw))*64 + sub*8);
        *(short8v*)(ftile + (row*18+col)*72 + sub*8) = v;
    }
    __syncthreads();

    const int row = 2*wave + (n>>4), col = n&15;
    const unsigned short* sfwf = (const unsigned short*)(ws + SFWf);
    const unsigned short* fcwf = (const unsigned short*)(ws + FCWf);
    float16v F0 = fzero16(), F1 = fzero16();

    #pragma unroll
    for(int og=0; og<2; og++){             // sf output group = fc input group
        // --- sf conv for this og: 36 MFMAs -> Y in D-layout regs ---
        float16v Y = fzero16();
        #pragma unroll
        for(int kc=0; kc<4; kc++){
            short8v af[9];
            #pragma unroll
            for(int tap=0; tap<9; tap++)
                af[tap] = *(const short8v*)(sfwf + (((size_t)og*36 + tap*4+kc)*64 + lane)*8);
            #pragma unroll
            for(int tap=0; tap<9; tap++){
                const int dh = tap/3, dw = tap%3;
                short8v bf = *(const short8v*)(ftile + ((row+dh)*18 + col+dw)*72
                                               + kc*16 + half*8);
                Y = __builtin_amdgcn_mfma_f32_32x32x16_bf16(af[tap], bf, Y, 0,0,0);
            }
        }
        // bias + relu -> bf16 (same numerics as prior ytile path)
        unsigned short yb[16];
        #pragma unroll
        for(int r=0;r<16;r++){
            float bias = ws[SFBo + og*32 + (r&3)+8*(r>>2)+4*half];
            yb[r] = f2bfu(fmaxf(Y[r] + bias, 0.f));
        }
        // --- build fc B-frags for kc_fc = 2*og + {0,1} via shfl exchange ---
        #pragma unroll
        for(int kcl=0; kcl<2; kcl++){
            const int kc_fc = 2*og + kcl;
            // low quad = regs 8kcl..+3, high quad = regs 8kcl+4..+7
            unsigned short l0,l1,l2,l3, s0,s1,s2,s3;
            if(half==0){ l0=yb[8*kcl+0]; l1=yb[8*kcl+1]; l2=yb[8*kcl+2]; l3=yb[8*kcl+3];
                         s0=yb[8*kcl+4]; s1=yb[8*kcl+5]; s2=yb[8*kcl+6]; s3=yb[8*kcl+7]; }
            else       { l0=yb[8*kcl+4]; l1=yb[8*kcl+5]; l2=yb[8*kcl+6]; l3=yb[8*kcl+7];
                         s0=yb[8*kcl+0]; s1=yb[8*kcl+1]; s2=yb[8*kcl+2]; s3=yb[8*kcl+3]; }
            int p0 = (int)((unsigned)s0 | ((unsigned)s1<<16));
            int p1 = (int)((unsigned)s2 | ((unsigned)s3<<16));
            int r0 = __shfl_xor(p0, 32);
            int r1 = __shfl_xor(p1, 32);
            unsigned short m0 = (unsigned short)(r0 & 0xffff);
            unsigned short m1 = (unsigned short)(((unsigned)r0) >> 16);
            unsigned short m2 = (unsigned short)(r1 & 0xffff);
            unsigned short m3 = (unsigned short)(((unsigned)r1) >> 16);
            short8v B;
            if(half==0){ B[0]=(short)l0; B[1]=(short)l1; B[2]=(short)l2; B[3]=(short)l3;
                         B[4]=(short)m0; B[5]=(short)m1; B[6]=(short)m2; B[7]=(short)m3; }
            else       { B[0]=(short)m0; B[1]=(short)m1; B[2]=(short)m2; B[3]=(short)m3;
                         B[4]=(short)l0; B[5]=(short)l1; B[6]=(short)l2; B[7]=(short)l3; }
            short8v fa0 = *(const short8v*)(fcwf + (((size_t)0*4 + kc_fc)*64 + lane)*8);
            short8v fa1 = *(const short8v*)(fcwf + (((size_t)1*4 + kc_fc)*64 + lane)*8);
            F0 = __builtin_amdgcn_mfma_f32_32x32x16_bf16(fa0, B, F0, 0,0,0);
            F1 = __builtin_amdgcn_mfma_f32_32x32x16_bf16(fa1, B, F1, 0,0,0);
        }
    }
    // --- epilogue: bias + residual -> fp32 NCHW out ---
    #pragma unroll
    for(int og=0; og<2; og++){
        #pragma unroll
        for(int r=0;r<16;r++){
            int oc = og*32 + (r&3)+8*(r>>2)+4*half;
            size_t g = ((size_t)(b*CC + oc))*HWs + (h0+row)*WW + w0 + col;
            float v = (og==0) ? F0[r] : F1[r];
            out[g] = v + fcb[oc] + x[g];
        }
    }
}

extern "C" void kernel_launch(void* const* d_in, const int* in_sizes, int n_in,
                              void* d_out, int out_size, void* d_ws, size_t ws_size,
                              hipStream_t stream)
{
    const float* x     = (const float*)d_in[0];
    const float* ba_w1 = (const float*)d_in[1];
    const float* ba_b1 = (const float*)d_in[2];
    const float* ba_w2 = (const float*)d_in[3];
    const float* ba_b2 = (const float*)d_in[4];
    // d_in[5..12] = offset branch: dead code in the reference (never reaches the output)
    const float* rk5_w = (const float*)d_in[13];
    const float* rk5_b = (const float*)d_in[14];
    const float* rk7_w = (const float*)d_in[15];
    const float* rk7_b = (const float*)d_in[16];
    const float* lk5_w = (const float*)d_in[17];
    const float* lk5_b = (const float*)d_in[18];
    const float* lk7_w = (const float*)d_in[19];
    const float* lk7_b = (const float*)d_in[20];
    const float* sf_w  = (const float*)d_in[21];
    const float* sf_b  = (const float*)d_in[22];
    const float* bng   = (const float*)d_in[23];
    const float* bnb   = (const float*)d_in[24];
    const float* bnm   = (const float*)d_in[25];
    const float* bnv   = (const float*)d_in[26];
    const float* fc_w  = (const float*)d_in[27];
    const float* fc_b  = (const float*)d_in[28];

    float* wsf = (float*)d_ws;
    unsigned short* XB  = (unsigned short*)((char*)d_ws + (size_t)WS_FLOATS*4);
    unsigned short* FUS = XB + (size_t)NPIX*64;
    float* out = (float*)d_out;

    k_prep<<<64, 256, 0, stream>>>(rk5_w,rk5_b,rk7_w,rk7_b,lk5_w,lk5_b,lk7_w,lk7_b,
                                   sf_w,sf_b,bng,bnb,bnm,bnv, ba_w1, fc_w, wsf);
    k_x2nhwc<<<NPIX/128, 256, 0, stream>>>(x, XB);
    k_fuseA<<<dim3(10,20,4), 256, 0, stream>>>(XB, ba_b1, ba_w2, ba_b2, wsf, FUS);
    k_fuseB<<<dim3(10,20,4), 256, 0, stream>>>(FUS, wsf, fc_b, x, out);
}